// Round 20
// baseline (414.967 us; speedup 1.0000x reference)
//
#include <hip/hip_runtime.h>
#include <hip/hip_bf16.h>
#include <stdint.h>

typedef __bf16 bf16;
typedef __bf16 bf16x2 __attribute__((ext_vector_type(2)));
typedef __bf16 bf16x4 __attribute__((ext_vector_type(4)));
typedef __bf16 bf16x8 __attribute__((ext_vector_type(8)));
typedef float f32x4 __attribute__((ext_vector_type(4)));
typedef float f32x16 __attribute__((ext_vector_type(16)));
typedef unsigned int u32;
typedef u32 u32x4 __attribute__((ext_vector_type(4)));
typedef unsigned long long u64;

#define MFMA16(a, b, c) __builtin_amdgcn_mfma_f32_16x16x32_bf16((a), (b), (c), 0, 0, 0)
#define MFMA32(a, b, c) __builtin_amdgcn_mfma_f32_32x32x16_bf16((a), (b), (c), 0, 0, 0)

constexpr int Bc = 2, Sc = 2048, Dc = 1024, Hc = 16, DKc = 64;
constexpr int Mc = Bc * Sc;
constexpr int MW = Sc / 64;
// 1/sqrt(dk) * log2(e): scores produced directly in log2 domain
#define QSCALE 0.1803368801111731f

__device__ __forceinline__ u32 pk2(float a, float b) {
  bf16x2 t; t[0] = (bf16)a; t[1] = (bf16)b;
  return __builtin_bit_cast(u32, t);
}

__device__ __forceinline__ void gl_lds16(const void* g, void* l) {
  __builtin_amdgcn_global_load_lds((const __attribute__((address_space(1))) void*)g,
                                   (__attribute__((address_space(3))) void*)l, 16, 0, 0);
}

// ---------------- fused prep: weight fp32->bf16 converts (y=0..3, Wq scaled) + mask pack (y=4) ----------------
__global__ __launch_bounds__(256) void prep_kernel(
    const float* __restrict__ wq, const float* __restrict__ wk,
    const float* __restrict__ wv, const float* __restrict__ wo,
    const int* __restrict__ mask,
    bf16* __restrict__ dwq, bf16* __restrict__ dwk, bf16* __restrict__ dwv,
    bf16* __restrict__ dwo, u64* __restrict__ mbT) {
  const int y = blockIdx.y;
  if (y == 4) {  // mask (int32 0/1) -> transposed bitmask mbT[b][kw][q]
    const int lane = threadIdx.x & 63;
    const int wid = (blockIdx.x * blockDim.x + threadIdx.x) >> 6;
    const int nw = (gridDim.x * blockDim.x) >> 6;
    const int nwords = Bc * Sc * Sc / 64;
    for (int i = wid; i < nwords; i += nw) {
      int vv = mask[(size_t)i * 64 + lane];
      u64 bits = __ballot(vv != 0);
      if (lane == 0) {
        const int kw = i & (MW - 1), bq = i >> 5;
        const int b = bq >> 11, qq = bq & (Sc - 1);
        mbT[((size_t)(b * MW + kw)) * Sc + qq] = bits;
      }
    }
    return;
  }
  const float* src; bf16* dst;
  switch (y) {
    case 0: src = wq; dst = dwq; break;
    case 1: src = wk; dst = dwk; break;
    case 2: src = wv; dst = dwv; break;
    default: src = wo; dst = dwo; break;
  }
  const size_t n = (size_t)Dc * Dc;
  const size_t i = ((size_t)blockIdx.x * 256 + threadIdx.x) * 8;
  if (i >= n) return;
  const float sc = (y == 0) ? QSCALE : 1.0f;
  f32x4 x0 = *(const f32x4*)&src[i];
  f32x4 x1 = *(const f32x4*)&src[i + 4];
  bf16x8 o;
#pragma unroll
  for (int j = 0; j < 4; ++j) { o[j] = (bf16)(x0[j] * sc); o[4 + j] = (bf16)(x1[j] * sc); }
  *(bf16x8*)&dst[i] = o;
}

// ---------------- fused QKV GEMM: fp32-A direct (convert at fragment read), 3 blocks/CU ----------------
__global__ __launch_bounds__(256, 3) void gemm_qkv_kernel(
    const float* __restrict__ q, const float* __restrict__ k, const float* __restrict__ v,
    const bf16* __restrict__ wq, const bf16* __restrict__ wk, const bf16* __restrict__ wv,
    const float* __restrict__ bq, const float* __restrict__ bk, const float* __restrict__ bv,
    bf16* __restrict__ qh, bf16* __restrict__ kh, bf16* __restrict__ vt) {
  __shared__ float As[128 * 64];
  __shared__ bf16 Bs[128 * 64];
  const int d = blockIdx.x;
  const int xcd = d & 7, idx = d >> 3;
  const int proj = idx >> 5, w = idx & 31;
  const int n0 = (w & 7) * 128;
  const int m0 = (xcd * 4 + (w >> 3)) * 128;
  const float* Af = proj == 0 ? q : proj == 1 ? k : v;
  const bf16* Bw = proj == 0 ? wq : proj == 1 ? wk : wv;
  const float* bias = proj == 0 ? bq : proj == 1 ? bk : bv;

  const int t = threadIdx.x, lane = t & 63, wv4 = t >> 6;
  const int c = lane & 15, g = lane >> 4;
  const int wr = wv4 >> 1, wc = wv4 & 1;

  f32x4 acc[4][4];
#pragma unroll
  for (int i = 0; i < 4; ++i)
#pragma unroll
    for (int j = 0; j < 4; ++j) acc[i][j] = (f32x4){0.f, 0.f, 0.f, 0.f};

  const int arow_l = lane >> 4;             // A: 4 rows per 1KB chunk, 16 slots/row
  const int aslot_l = lane & 15;
  const int brow_l = lane >> 3;             // B: 8 rows per 1KB chunk
  const int bslot_l = (lane & 7) ^ brow_l;

  for (int k0 = 0; k0 < Dc; k0 += 64) {
#pragma unroll
    for (int u = 0; u < 8; ++u) {
      const int ch = wv4 * 8 + u;
      const int row = ch * 4 + arow_l;
      const int slot = aslot_l ^ (row & 7);
      gl_lds16(&Af[(size_t)(m0 + row) * Dc + k0 + slot * 4], &As[ch * 256]);
    }
#pragma unroll
    for (int u = 0; u < 4; ++u) {
      const int ch = wv4 * 4 + u;
      const int row = ch * 8 + brow_l;
      gl_lds16(&Bw[(size_t)(n0 + row) * Dc + k0 + bslot_l * 8], &Bs[ch * 512]);
    }
    __syncthreads();
#pragma unroll
    for (int ks = 0; ks < 2; ++ks) {
      bf16x8 af[4], bfr[4];
#pragma unroll
      for (int mt = 0; mt < 4; ++mt) {
        const int row = wr * 64 + mt * 16 + c;
        const int s0 = (8 * ks + 2 * g) ^ (c & 7);
        const int s1 = (8 * ks + 2 * g + 1) ^ (c & 7);
        f32x4 lo = *(const f32x4*)&As[row * 64 + s0 * 4];
        f32x4 hi2 = *(const f32x4*)&As[row * 64 + s1 * 4];
#pragma unroll
        for (int j = 0; j < 4; ++j) { af[mt][j] = (bf16)lo[j]; af[mt][4 + j] = (bf16)hi2[j]; }
      }
#pragma unroll
      for (int nt = 0; nt < 4; ++nt) {
        const int row = wc * 64 + nt * 16 + c;
        const int sl = (4 * ks + g) ^ (c & 7);
        bfr[nt] = *(const bf16x8*)&Bs[row * 64 + sl * 8];
      }
#pragma unroll
      for (int mt = 0; mt < 4; ++mt)
#pragma unroll
        for (int nt = 0; nt < 4; ++nt) acc[mt][nt] = MFMA16(af[mt], bfr[nt], acc[mt][nt]);
    }
    __syncthreads();
  }

  const float bsc = proj == 0 ? QSCALE : 1.0f;
  const int colb = n0 + wc * 64 + c;
  const int mrowb = m0 + wr * 64 + 4 * g;
#pragma unroll
  for (int mt = 0; mt < 4; ++mt) {
#pragma unroll
    for (int nt = 0; nt < 4; ++nt) {
      const int col = colb + nt * 16;
      const int mrow = mrowb + mt * 16;
      const float bb = bias[col] * bsc;
      f32x4 a = acc[mt][nt];
      if (proj == 0) {
#pragma unroll
        for (int r = 0; r < 4; ++r) qh[(size_t)(mrow + r) * Dc + col] = (bf16)(a[r] + bb);
      } else if (proj == 1) {
        const int hh = col >> 6, dd = col & 63;
#pragma unroll
        for (int r = 0; r < 4; ++r) {
          const int mr = mrow + r;
          kh[((size_t)((mr >> 11) * Hc + hh) * Sc + (mr & (Sc - 1))) * DKc + dd] = (bf16)(a[r] + bb);
        }
      } else {
        // V: transposed [B][H][64][S] with s bits 2<->3 swapped (PV b128 fragment layout)
        const int batch = mrow >> 11, s = mrow & (Sc - 1);
        const int s2 = (s & ~15) | ((s & 4) << 1) | ((s & 8) >> 1);
        const int hh = col >> 6, dd = col & 63;
        bf16x4 pkv;
#pragma unroll
        for (int r = 0; r < 4; ++r) pkv[r] = (bf16)(a[r] + bb);
        *(bf16x4*)&vt[((size_t)((batch * Hc + hh) * DKc + dd)) * Sc + s2] = pkv;
      }
    }
  }
}

// ---------------- output GEMM: BM=64 BN=64, 4 blocks/CU (bf16 ctx input) ----------------
__global__ __launch_bounds__(256, 4) void gemm_o_kernel(const bf16* __restrict__ ctxp,
                                                        const bf16* __restrict__ wo,
                                                        const float* __restrict__ bo,
                                                        float* __restrict__ outp) {
  __shared__ bf16 As[64 * 64];
  __shared__ bf16 Bs[64 * 64];
  const int d = blockIdx.x;
  const int xcd = d & 7, idx = d >> 3;             // 1024 blocks, XCD-chunked
  const int m0 = (xcd * 8 + (idx >> 4)) * 64;      // 64 m-panels of 64 rows
  const int n0 = (idx & 15) * 64;

  const int t = threadIdx.x, lane = t & 63, wv = t >> 6;
  const int c = lane & 15, g = lane >> 4;
  const int brow_l = lane >> 3;
  const int bslot_l = (lane & 7) ^ brow_l;

  const int myrow = wv * 16 + c;                   // this lane's A-fragment row

  f32x4 acc[4];
#pragma unroll
  for (int j = 0; j < 4; ++j) acc[j] = (f32x4){0.f, 0.f, 0.f, 0.f};

  for (int k0 = 0; k0 < Dc; k0 += 64) {
    {
      const int row = wv * 8 + brow_l;             // A: 8 chunks, 2 per wave
      gl_lds16(&ctxp[(size_t)(m0 + row) * Dc + k0 + bslot_l * 8], &As[wv * 512]);
      const int row2 = (wv + 4) * 8 + brow_l;
      gl_lds16(&ctxp[(size_t)(m0 + row2) * Dc + k0 + bslot_l * 8], &As[(wv + 4) * 512]);
    }
    {
      const int row = wv * 8 + brow_l;             // B: 8 chunks, 2 per wave
      gl_lds16(&wo[(size_t)(n0 + row) * Dc + k0 + bslot_l * 8], &Bs[wv * 512]);
      const int row2 = (wv + 4) * 8 + brow_l;
      gl_lds16(&wo[(size_t)(n0 + row2) * Dc + k0 + bslot_l * 8], &Bs[(wv + 4) * 512]);
    }
    __syncthreads();
#pragma unroll
    for (int ks = 0; ks < 2; ++ks) {
      const int sl = (4 * ks + g) ^ (c & 7);
      bf16x8 af = *(const bf16x8*)&As[myrow * 64 + ((4 * ks + g) ^ (myrow & 7)) * 8];
#pragma unroll
      for (int nt = 0; nt < 4; ++nt) {
        const int row = nt * 16 + c;
        bf16x8 bfr = *(const bf16x8*)&Bs[row * 64 + sl * 8];
        acc[nt] = MFMA16(af, bfr, acc[nt]);
      }
    }
    __syncthreads();
  }

  const int colb = n0 + c;
  const int mrowb = m0 + wv * 16 + 4 * g;
#pragma unroll
  for (int nt = 0; nt < 4; ++nt) {
    const int col = colb + nt * 16;
    const float bb = bo[col];
    f32x4 a = acc[nt];
#pragma unroll
    for (int r = 0; r < 4; ++r) outp[(size_t)(mrowb + r) * Dc + col] = a[r] + bb;
  }
}

// ---------------- flash attention: R18 body, generic splits (runtime tile range), 6 waves/EU ----------------
template <int SPLITS>
__global__ __launch_bounds__(512, 6) void attn_kernel(const bf16* __restrict__ qh,
                                                      const bf16* __restrict__ kh,
                                                      const bf16* __restrict__ vt,
                                                      const u64* __restrict__ mbT,
                                                      bf16* __restrict__ ctx,
                                                      bf16* __restrict__ opart,
                                                      float* __restrict__ lsums) {
  __shared__ bf16 Ks[2][64 * 64];   // [buf][k-row 64][64], 16B slots XOR-swizzled by row&7
  __shared__ bf16 Vs[2][64 * 64];   // [buf][d-row 64][64 perm k], same swizzle
  const int d = blockIdx.x;
  const int xcd = d & 7, idx = d >> 3;
  const int bh = xcd * 4 + idx / (8 * SPLITS);
  const int sub = idx % (8 * SPLITS);
  const int qt = sub / SPLITS, half = sub % SPLITS;
  const int b = bh >> 4, h = bh & 15;
  const int lane = threadIdx.x & 63, wv8 = threadIdx.x >> 6;   // 8 waves
  const int ql = lane & 31, hi = lane >> 5;
  const int qrow = qt * 256 + wv8 * 32 + ql;

  const bf16* Qp = qh + (size_t)(b * Sc + qrow) * Dc + h * DKc;
  const bf16* Kp = kh + (size_t)(b * Hc + h) * Sc * DKc;
  const bf16* Vp = vt + (size_t)(b * Hc + h) * DKc * Sc;
  const u64* mbp = mbT + (size_t)b * MW * Sc;  // [kw][q], q-coalesced

  // uneven-safe tile range: tiles [t0, t1) of the 32 KV tiles
  const int t0 = (half * (Sc / 64)) / SPLITS;
  const int t1 = ((half + 1) * (Sc / 64)) / SPLITS;
  const int k0 = t0 * 64;
  const int nit = t1 - t0;

  const int srow = lane >> 3, sslot = lane & 7;  // staging: 1 K chunk + 1 V chunk per wave
  auto stage = [&](int buf, int kt) {
    const int r = wv8 * 8 + srow;                // r&7 == srow (chunks 8-row aligned)
    gl_lds16(&Kp[(size_t)(kt + r) * DKc + (size_t)((sslot ^ srow) * 8)], &Ks[buf][wv8 * 512]);
    gl_lds16(&Vp[(size_t)r * Sc + kt + (size_t)((sslot ^ srow) * 8)], &Vs[buf][wv8 * 512]);
  };

  bf16x8 qf[4];
#pragma unroll
  for (int ka = 0; ka < 4; ++ka) qf[ka] = *(const bf16x8*)&Qp[16 * ka + 8 * hi];

  bf16x8 ones8;
#pragma unroll
  for (int j = 0; j < 8; ++j) ones8[j] = (bf16)1.0f;

  f32x16 oacc[2], lacc;
#pragma unroll
  for (int i = 0; i < 2; ++i)
#pragma unroll
    for (int r = 0; r < 16; ++r) oacc[i][r] = 0.f;
#pragma unroll
  for (int r = 0; r < 16; ++r) lacc[r] = 0.f;

  // prologue: stage tile 0 + its mask word (coalesced), drain, barrier
  stage(0, k0);
  u64 w = mbp[(size_t)(k0 >> 6) * Sc + qrow];
  asm volatile("s_waitcnt vmcnt(0)" ::: "memory");
  __builtin_amdgcn_s_barrier();
  __builtin_amdgcn_sched_barrier(0);

  for (int it = 0; it < nit; ++it) {
    const int kt = k0 + it * 64;
    const int buf = it & 1;
    const int ktn = (it + 1 < nit) ? kt + 64 : kt;  // clamp: harmless restage on last iter
    stage(buf ^ 1, ktn);
    const u64 wn = mbp[(size_t)(ktn >> 6) * Sc + qrow];

    // ---- QK^T from LDS: st[tt] covers k in [kt+32tt, +32), all 32 q ----
    f32x16 st[2];
#pragma unroll
    for (int tt = 0; tt < 2; ++tt) {
      const int row = 32 * tt + ql;
      const bf16* kbase = &Ks[buf][row * 64];
      f32x16 z;
#pragma unroll
      for (int r = 0; r < 16; ++r) z[r] = 0.f;
      __builtin_amdgcn_s_setprio(1);
#pragma unroll
      for (int ka = 0; ka < 4; ++ka) {
        bf16x8 kf = *(const bf16x8*)&kbase[((2 * ka + hi) ^ (row & 7)) * 8];
        z = MFMA32(kf, qf[ka], z);
      }
      __builtin_amdgcn_s_setprio(0);
      st[tt] = z;
    }

    // ---- fixed-base softmax: p = exp2(s) raw (scale cancels in o = sum(p*v)/sum(p)) ----
    const u32 wt0 = (u32)(w >> (4 * hi));
    const u32 wt1 = (u32)(w >> (32 + 4 * hi));
#pragma unroll
    for (int tt = 0; tt < 2; ++tt) {
      const u32 wt = tt ? wt1 : wt0;
#pragma unroll
      for (int r = 0; r < 16; ++r) {
        const int bit = (r & 3) + 8 * (r >> 2);
        const float p = __builtin_amdgcn_exp2f((float)st[tt][r]);
        st[tt][r] = ((wt >> bit) & 1u) ? p : 0.f;
      }
    }

    // ---- pb = straight pack of st under the shared k-map ----
    u32x4 pb[4];
#pragma unroll
    for (int ks = 0; ks < 4; ++ks) {
      const int tt = ks >> 1, e = ks & 1;
#pragma unroll
      for (int w2 = 0; w2 < 4; ++w2)
        pb[ks][w2] = pk2((float)st[tt][8 * e + 2 * w2], (float)st[tt][8 * e + 2 * w2 + 1]);
    }

    // ---- l += colsum via ones-MFMA; PV with single-b128 V-frags ----
    __builtin_amdgcn_s_setprio(1);
#pragma unroll
    for (int ks = 0; ks < 4; ++ks)
      lacc = MFMA32(ones8, __builtin_bit_cast(bf16x8, pb[ks]), lacc);
#pragma unroll
    for (int dt = 0; dt < 2; ++dt) {
      const int row = 32 * dt + ql;
      const bf16* vbase = &Vs[buf][row * 64];
#pragma unroll
      for (int ks = 0; ks < 4; ++ks) {
        bf16x8 vf = *(const bf16x8*)&vbase[((2 * ks + hi) ^ (row & 7)) * 8];
        oacc[dt] = MFMA32(vf, __builtin_bit_cast(bf16x8, pb[ks]), oacc[dt]);
      }
    }
    __builtin_amdgcn_s_setprio(0);

    // stage + mask ops were issued a full compute ago -> retire instantly
    asm volatile("s_waitcnt vmcnt(0)" ::: "memory");
    __builtin_amdgcn_s_barrier();
    __builtin_amdgcn_sched_barrier(0);
    w = wn;
  }

  const float lsum = lacc[0];  // every reg row holds the same column-sum
  if constexpr (SPLITS > 1) {
    bf16* opr = opart + ((size_t)(half * 32 + bh) * Sc + qrow) * 64;
#pragma unroll
    for (int dt = 0; dt < 2; ++dt)
#pragma unroll
      for (int i = 0; i < 4; ++i) {
        bf16x4 o4;
#pragma unroll
        for (int rr = 0; rr < 4; ++rr) o4[rr] = (bf16)oacc[dt][4 * i + rr];
        *(bf16x4*)&opr[32 * dt + 8 * i + 4 * hi] = o4;
      }
    if (hi == 0) lsums[(size_t)(half * 32 + bh) * Sc + qrow] = lsum;
  } else {
    const float rinv = 1.f / fmaxf(lsum, 1e-35f);
    bf16* cp = ctx + (size_t)(b * Sc + qrow) * Dc + h * DKc;
#pragma unroll
    for (int dt = 0; dt < 2; ++dt)
#pragma unroll
      for (int i = 0; i < 4; ++i) {
        bf16x4 o4;
#pragma unroll
        for (int rr = 0; rr < 4; ++rr) o4[rr] = (bf16)(oacc[dt][4 * i + rr] * rinv);
        *(bf16x4*)&cp[32 * dt + 8 * i + 4 * hi] = o4;
      }
  }
}

// ---------------- combine NS fixed-base splits (bf16 partials, f32 l-sums) ----------------
template <int NS>
__global__ __launch_bounds__(256) void combine_kernel(const bf16* __restrict__ op,
                                                      const float* __restrict__ ls,
                                                      bf16* __restrict__ ctx) {
  const int wv = threadIdx.x >> 6, lane = threadIdx.x & 63;
  const size_t row = (size_t)blockIdx.x * 4 + wv;      // bh*2048 + q, 0..65535
  const int bh = (int)(row >> 11), q = (int)(row & 2047);
  const int b = bh >> 4, h = bh & 15;
  float o = 0.f, l = 0.f;
#pragma unroll
  for (int s = 0; s < NS; ++s) {
    o += (float)op[(size_t)s * 65536 * 64 + row * 64 + lane];
    l += ls[(size_t)s * 65536 + row];
  }
  ctx[((size_t)(b * Sc + q)) * Dc + h * DKc + lane] = (bf16)(o / fmaxf(l, 1e-35f));
}

extern "C" void kernel_launch(void* const* d_in, const int* in_sizes, int n_in,
                              void* d_out, int out_size, void* d_ws, size_t ws_size,
                              hipStream_t stream) {
  (void)in_sizes; (void)n_in; (void)out_size;
  const float* q  = (const float*)d_in[0];
  const float* k  = (const float*)d_in[1];
  const float* v  = (const float*)d_in[2];
  const float* Wq = (const float*)d_in[3];
  const float* bq = (const float*)d_in[4];
  const float* Wk = (const float*)d_in[5];
  const float* bk = (const float*)d_in[6];
  const float* Wv = (const float*)d_in[7];
  const float* bv = (const float*)d_in[8];
  const float* Wo = (const float*)d_in[9];
  const float* bo = (const float*)d_in[10];
  const int* mask = (const int*)d_in[11];

  char* ws = (char*)d_ws;
  size_t off = 0;
  auto take = [&](size_t bytes) -> void* {
    void* p = ws + off;
    off += (bytes + 255) & ~(size_t)255;
    return p;
  };
  bf16* qh  = (bf16*)take((size_t)Mc * Dc * 2);
  bf16* kh  = (bf16*)take((size_t)Mc * Dc * 2);
  bf16* vt  = (bf16*)take((size_t)Mc * Dc * 2);
  bf16* ctx = (bf16*)take((size_t)Mc * Dc * 2);
  u64* mbits = (u64*)take((size_t)Bc * Sc * MW * 8);   // transposed: [b][kw][q]
  bf16* wqb = (bf16*)take((size_t)Dc * Dc * 2);
  bf16* wkb = (bf16*)take((size_t)Dc * Dc * 2);
  bf16* wvb = (bf16*)take((size_t)Dc * Dc * 2);
  bf16* wob = (bf16*)take((size_t)Dc * Dc * 2);

  // split-KV partials: bf16 [split][bh][q][64] + f32 l [split][bh][q]; try 3 splits, then 2
  const size_t opart_sz = (size_t)32 * Sc * 64 * 2;    // per split (bf16)
  const size_t ls_sz    = (size_t)32 * Sc * 4;         // per split (f32)
  int splits = 1;
  bf16* opart = nullptr; float* lsums = nullptr;
  for (int s = 3; s >= 2; --s) {
    if (off + (opart_sz + ls_sz) * s <= ws_size) {
      splits = s;
      opart = (bf16*)(ws + off);
      lsums = (float*)(ws + off + opart_sz * s);
      break;
    }
  }

  prep_kernel<<<dim3(2048, 5), 256, 0, stream>>>(Wq, Wk, Wv, Wo, mask,
                                                 wqb, wkb, wvb, wob, mbits);
  gemm_qkv_kernel<<<768, 256, 0, stream>>>(q, k, v, wqb, wkb, wvb, bq, bk, bv, qh, kh, vt);
  if (splits == 3) {
    attn_kernel<3><<<768, 512, 0, stream>>>(qh, kh, vt, mbits, ctx, opart, lsums);
    combine_kernel<3><<<16384, 256, 0, stream>>>(opart, lsums, ctx);
  } else if (splits == 2) {
    attn_kernel<2><<<512, 512, 0, stream>>>(qh, kh, vt, mbits, ctx, opart, lsums);
    combine_kernel<2><<<16384, 256, 0, stream>>>(opart, lsums, ctx);
  } else {
    attn_kernel<1><<<256, 512, 0, stream>>>(qh, kh, vt, mbits, ctx, opart, lsums);
  }
  gemm_o_kernel<<<1024, 256, 0, stream>>>(ctx, wob, bo, (float*)d_out);
}

// Round 21
// 144.801 us; speedup vs baseline: 2.8658x; 2.8658x over previous
//
#include <hip/hip_runtime.h>
#include <hip/hip_bf16.h>
#include <stdint.h>

typedef __bf16 bf16;
typedef __bf16 bf16x2 __attribute__((ext_vector_type(2)));
typedef __bf16 bf16x4 __attribute__((ext_vector_type(4)));
typedef __bf16 bf16x8 __attribute__((ext_vector_type(8)));
typedef float f32x4 __attribute__((ext_vector_type(4)));
typedef float f32x16 __attribute__((ext_vector_type(16)));
typedef unsigned int u32;
typedef u32 u32x4 __attribute__((ext_vector_type(4)));
typedef unsigned long long u64;

#define MFMA16(a, b, c) __builtin_amdgcn_mfma_f32_16x16x32_bf16((a), (b), (c), 0, 0, 0)
#define MFMA32(a, b, c) __builtin_amdgcn_mfma_f32_32x32x16_bf16((a), (b), (c), 0, 0, 0)

constexpr int Bc = 2, Sc = 2048, Dc = 1024, Hc = 16, DKc = 64;
constexpr int Mc = Bc * Sc;
constexpr int MW = Sc / 64;
// 1/sqrt(dk) * log2(e): scores produced directly in log2 domain
#define QSCALE 0.1803368801111731f

__device__ __forceinline__ u32 pk2(float a, float b) {
  bf16x2 t; t[0] = (bf16)a; t[1] = (bf16)b;
  return __builtin_bit_cast(u32, t);
}

__device__ __forceinline__ void gl_lds16(const void* g, void* l) {
  __builtin_amdgcn_global_load_lds((const __attribute__((address_space(1))) void*)g,
                                   (__attribute__((address_space(3))) void*)l, 16, 0, 0);
}

// ---------------- fused prep: weight fp32->bf16 converts (y=0..3, Wq scaled) + mask pack (y=4) ----------------
__global__ __launch_bounds__(256) void prep_kernel(
    const float* __restrict__ wq, const float* __restrict__ wk,
    const float* __restrict__ wv, const float* __restrict__ wo,
    const int* __restrict__ mask,
    bf16* __restrict__ dwq, bf16* __restrict__ dwk, bf16* __restrict__ dwv,
    bf16* __restrict__ dwo, u64* __restrict__ mbT) {
  const int y = blockIdx.y;
  if (y == 4) {  // mask (int32 0/1) -> transposed bitmask mbT[b][kw][q]
    const int lane = threadIdx.x & 63;
    const int wid = (blockIdx.x * blockDim.x + threadIdx.x) >> 6;
    const int nw = (gridDim.x * blockDim.x) >> 6;
    const int nwords = Bc * Sc * Sc / 64;
    for (int i = wid; i < nwords; i += nw) {
      int vv = mask[(size_t)i * 64 + lane];
      u64 bits = __ballot(vv != 0);
      if (lane == 0) {
        const int kw = i & (MW - 1), bq = i >> 5;
        const int b = bq >> 11, qq = bq & (Sc - 1);
        mbT[((size_t)(b * MW + kw)) * Sc + qq] = bits;
      }
    }
    return;
  }
  const float* src; bf16* dst;
  switch (y) {
    case 0: src = wq; dst = dwq; break;
    case 1: src = wk; dst = dwk; break;
    case 2: src = wv; dst = dwv; break;
    default: src = wo; dst = dwo; break;
  }
  const size_t n = (size_t)Dc * Dc;
  const size_t i = ((size_t)blockIdx.x * 256 + threadIdx.x) * 8;
  if (i >= n) return;
  const float sc = (y == 0) ? QSCALE : 1.0f;
  f32x4 x0 = *(const f32x4*)&src[i];
  f32x4 x1 = *(const f32x4*)&src[i + 4];
  bf16x8 o;
#pragma unroll
  for (int j = 0; j < 4; ++j) { o[j] = (bf16)(x0[j] * sc); o[4 + j] = (bf16)(x1[j] * sc); }
  *(bf16x8*)&dst[i] = o;
}

// ---------------- fused QKV GEMM: fp32-A direct (convert at fragment read), 3 blocks/CU ----------------
__global__ __launch_bounds__(256, 3) void gemm_qkv_kernel(
    const float* __restrict__ q, const float* __restrict__ k, const float* __restrict__ v,
    const bf16* __restrict__ wq, const bf16* __restrict__ wk, const bf16* __restrict__ wv,
    const float* __restrict__ bq, const float* __restrict__ bk, const float* __restrict__ bv,
    bf16* __restrict__ qh, bf16* __restrict__ kh, bf16* __restrict__ vt) {
  __shared__ float As[128 * 64];
  __shared__ bf16 Bs[128 * 64];
  const int d = blockIdx.x;
  const int xcd = d & 7, idx = d >> 3;
  const int proj = idx >> 5, w = idx & 31;
  const int n0 = (w & 7) * 128;
  const int m0 = (xcd * 4 + (w >> 3)) * 128;
  const float* Af = proj == 0 ? q : proj == 1 ? k : v;
  const bf16* Bw = proj == 0 ? wq : proj == 1 ? wk : wv;
  const float* bias = proj == 0 ? bq : proj == 1 ? bk : bv;

  const int t = threadIdx.x, lane = t & 63, wv4 = t >> 6;
  const int c = lane & 15, g = lane >> 4;
  const int wr = wv4 >> 1, wc = wv4 & 1;

  f32x4 acc[4][4];
#pragma unroll
  for (int i = 0; i < 4; ++i)
#pragma unroll
    for (int j = 0; j < 4; ++j) acc[i][j] = (f32x4){0.f, 0.f, 0.f, 0.f};

  const int arow_l = lane >> 4;             // A: 4 rows per 1KB chunk, 16 slots/row
  const int aslot_l = lane & 15;
  const int brow_l = lane >> 3;             // B: 8 rows per 1KB chunk
  const int bslot_l = (lane & 7) ^ brow_l;

  for (int k0 = 0; k0 < Dc; k0 += 64) {
#pragma unroll
    for (int u = 0; u < 8; ++u) {
      const int ch = wv4 * 8 + u;
      const int row = ch * 4 + arow_l;
      const int slot = aslot_l ^ (row & 7);
      gl_lds16(&Af[(size_t)(m0 + row) * Dc + k0 + slot * 4], &As[ch * 256]);
    }
#pragma unroll
    for (int u = 0; u < 4; ++u) {
      const int ch = wv4 * 4 + u;
      const int row = ch * 8 + brow_l;
      gl_lds16(&Bw[(size_t)(n0 + row) * Dc + k0 + bslot_l * 8], &Bs[ch * 512]);
    }
    __syncthreads();
#pragma unroll
    for (int ks = 0; ks < 2; ++ks) {
      bf16x8 af[4], bfr[4];
#pragma unroll
      for (int mt = 0; mt < 4; ++mt) {
        const int row = wr * 64 + mt * 16 + c;
        const int s0 = (8 * ks + 2 * g) ^ (c & 7);
        const int s1 = (8 * ks + 2 * g + 1) ^ (c & 7);
        f32x4 lo = *(const f32x4*)&As[row * 64 + s0 * 4];
        f32x4 hi2 = *(const f32x4*)&As[row * 64 + s1 * 4];
#pragma unroll
        for (int j = 0; j < 4; ++j) { af[mt][j] = (bf16)lo[j]; af[mt][4 + j] = (bf16)hi2[j]; }
      }
#pragma unroll
      for (int nt = 0; nt < 4; ++nt) {
        const int row = wc * 64 + nt * 16 + c;
        const int sl = (4 * ks + g) ^ (c & 7);
        bfr[nt] = *(const bf16x8*)&Bs[row * 64 + sl * 8];
      }
#pragma unroll
      for (int mt = 0; mt < 4; ++mt)
#pragma unroll
        for (int nt = 0; nt < 4; ++nt) acc[mt][nt] = MFMA16(af[mt], bfr[nt], acc[mt][nt]);
    }
    __syncthreads();
  }

  const float bsc = proj == 0 ? QSCALE : 1.0f;
  const int colb = n0 + wc * 64 + c;
  const int mrowb = m0 + wr * 64 + 4 * g;
#pragma unroll
  for (int mt = 0; mt < 4; ++mt) {
#pragma unroll
    for (int nt = 0; nt < 4; ++nt) {
      const int col = colb + nt * 16;
      const int mrow = mrowb + mt * 16;
      const float bb = bias[col] * bsc;
      f32x4 a = acc[mt][nt];
      if (proj == 0) {
#pragma unroll
        for (int r = 0; r < 4; ++r) qh[(size_t)(mrow + r) * Dc + col] = (bf16)(a[r] + bb);
      } else if (proj == 1) {
        const int hh = col >> 6, dd = col & 63;
#pragma unroll
        for (int r = 0; r < 4; ++r) {
          const int mr = mrow + r;
          kh[((size_t)((mr >> 11) * Hc + hh) * Sc + (mr & (Sc - 1))) * DKc + dd] = (bf16)(a[r] + bb);
        }
      } else {
        // V: transposed [B][H][64][S] with s bits 2<->3 swapped (PV b128 fragment layout)
        const int batch = mrow >> 11, s = mrow & (Sc - 1);
        const int s2 = (s & ~15) | ((s & 4) << 1) | ((s & 8) >> 1);
        const int hh = col >> 6, dd = col & 63;
        bf16x4 pkv;
#pragma unroll
        for (int r = 0; r < 4; ++r) pkv[r] = (bf16)(a[r] + bb);
        *(bf16x4*)&vt[((size_t)((batch * Hc + hh) * DKc + dd)) * Sc + s2] = pkv;
      }
    }
  }
}

// ---------------- output GEMM: BM=64 BN=64, 4 blocks/CU (bf16 ctx input) ----------------
__global__ __launch_bounds__(256, 4) void gemm_o_kernel(const bf16* __restrict__ ctxp,
                                                        const bf16* __restrict__ wo,
                                                        const float* __restrict__ bo,
                                                        float* __restrict__ outp) {
  __shared__ bf16 As[64 * 64];
  __shared__ bf16 Bs[64 * 64];
  const int d = blockIdx.x;
  const int xcd = d & 7, idx = d >> 3;             // 1024 blocks, XCD-chunked
  const int m0 = (xcd * 8 + (idx >> 4)) * 64;      // 64 m-panels of 64 rows
  const int n0 = (idx & 15) * 64;

  const int t = threadIdx.x, lane = t & 63, wv = t >> 6;
  const int c = lane & 15, g = lane >> 4;
  const int brow_l = lane >> 3;
  const int bslot_l = (lane & 7) ^ brow_l;

  const int myrow = wv * 16 + c;                   // this lane's A-fragment row

  f32x4 acc[4];
#pragma unroll
  for (int j = 0; j < 4; ++j) acc[j] = (f32x4){0.f, 0.f, 0.f, 0.f};

  for (int k0 = 0; k0 < Dc; k0 += 64) {
    {
      const int row = wv * 8 + brow_l;             // A: 8 chunks, 2 per wave
      gl_lds16(&ctxp[(size_t)(m0 + row) * Dc + k0 + bslot_l * 8], &As[wv * 512]);
      const int row2 = (wv + 4) * 8 + brow_l;
      gl_lds16(&ctxp[(size_t)(m0 + row2) * Dc + k0 + bslot_l * 8], &As[(wv + 4) * 512]);
    }
    {
      const int row = wv * 8 + brow_l;             // B: 8 chunks, 2 per wave
      gl_lds16(&wo[(size_t)(n0 + row) * Dc + k0 + bslot_l * 8], &Bs[wv * 512]);
      const int row2 = (wv + 4) * 8 + brow_l;
      gl_lds16(&wo[(size_t)(n0 + row2) * Dc + k0 + bslot_l * 8], &Bs[(wv + 4) * 512]);
    }
    __syncthreads();
#pragma unroll
    for (int ks = 0; ks < 2; ++ks) {
      const int sl = (4 * ks + g) ^ (c & 7);
      bf16x8 af = *(const bf16x8*)&As[myrow * 64 + ((4 * ks + g) ^ (myrow & 7)) * 8];
#pragma unroll
      for (int nt = 0; nt < 4; ++nt) {
        const int row = nt * 16 + c;
        bf16x8 bfr = *(const bf16x8*)&Bs[row * 64 + sl * 8];
        acc[nt] = MFMA16(af, bfr, acc[nt]);
      }
    }
    __syncthreads();
  }

  const int colb = n0 + c;
  const int mrowb = m0 + wv * 16 + 4 * g;
#pragma unroll
  for (int nt = 0; nt < 4; ++nt) {
    const int col = colb + nt * 16;
    const float bb = bo[col];
    f32x4 a = acc[nt];
#pragma unroll
    for (int r = 0; r < 4; ++r) outp[(size_t)(mrowb + r) * Dc + col] = a[r] + bb;
  }
}

// ---------------- flash attention: R18/R19 exact body (4 waves/EU, no spill) ----------------
template <int SPLITS>
__global__ __launch_bounds__(512, 4) void attn_kernel(const bf16* __restrict__ qh,
                                                      const bf16* __restrict__ kh,
                                                      const bf16* __restrict__ vt,
                                                      const u64* __restrict__ mbT,
                                                      bf16* __restrict__ ctx,
                                                      bf16* __restrict__ opart,
                                                      float* __restrict__ lsums) {
  __shared__ bf16 Ks[2][64 * 64];   // [buf][k-row 64][64], 16B slots XOR-swizzled by row&7
  __shared__ bf16 Vs[2][64 * 64];   // [buf][d-row 64][64 perm k], same swizzle
  const int d = blockIdx.x;
  const int xcd = d & 7, idx = d >> 3;
  const int bh = xcd * 4 + idx / (8 * SPLITS);
  const int sub = idx % (8 * SPLITS);
  const int qt = sub / SPLITS, half = sub % SPLITS;
  const int b = bh >> 4, h = bh & 15;
  const int lane = threadIdx.x & 63, wv8 = threadIdx.x >> 6;   // 8 waves
  const int ql = lane & 31, hi = lane >> 5;
  const int qrow = qt * 256 + wv8 * 32 + ql;

  const bf16* Qp = qh + (size_t)(b * Sc + qrow) * Dc + h * DKc;
  const bf16* Kp = kh + (size_t)(b * Hc + h) * Sc * DKc;
  const bf16* Vp = vt + (size_t)(b * Hc + h) * DKc * Sc;
  const u64* mbp = mbT + (size_t)b * MW * Sc;  // [kw][q], q-coalesced

  const int k0 = half * (Sc / SPLITS);
  constexpr int NIT = (Sc / SPLITS) / 64;

  const int srow = lane >> 3, sslot = lane & 7;  // staging: 1 K chunk + 1 V chunk per wave
  auto stage = [&](int buf, int kt) {
    const int r = wv8 * 8 + srow;                // r&7 == srow (chunks 8-row aligned)
    gl_lds16(&Kp[(size_t)(kt + r) * DKc + (size_t)((sslot ^ srow) * 8)], &Ks[buf][wv8 * 512]);
    gl_lds16(&Vp[(size_t)r * Sc + kt + (size_t)((sslot ^ srow) * 8)], &Vs[buf][wv8 * 512]);
  };

  bf16x8 qf[4];
#pragma unroll
  for (int ka = 0; ka < 4; ++ka) qf[ka] = *(const bf16x8*)&Qp[16 * ka + 8 * hi];

  bf16x8 ones8;
#pragma unroll
  for (int j = 0; j < 8; ++j) ones8[j] = (bf16)1.0f;

  f32x16 oacc[2], lacc;
#pragma unroll
  for (int i = 0; i < 2; ++i)
#pragma unroll
    for (int r = 0; r < 16; ++r) oacc[i][r] = 0.f;
#pragma unroll
  for (int r = 0; r < 16; ++r) lacc[r] = 0.f;

  // prologue: stage tile 0 + its mask word (coalesced), drain, barrier
  stage(0, k0);
  u64 w = mbp[(size_t)(k0 >> 6) * Sc + qrow];
  asm volatile("s_waitcnt vmcnt(0)" ::: "memory");
  __builtin_amdgcn_s_barrier();
  __builtin_amdgcn_sched_barrier(0);

  for (int it = 0; it < NIT; ++it) {
    const int kt = k0 + it * 64;
    const int buf = it & 1;
    const int ktn = (it + 1 < NIT) ? kt + 64 : kt;  // clamp: harmless restage on last iter
    stage(buf ^ 1, ktn);
    const u64 wn = mbp[(size_t)(ktn >> 6) * Sc + qrow];

    // ---- QK^T from LDS: st[tt] covers k in [kt+32tt, +32), all 32 q ----
    f32x16 st[2];
#pragma unroll
    for (int tt = 0; tt < 2; ++tt) {
      const int row = 32 * tt + ql;
      const bf16* kbase = &Ks[buf][row * 64];
      f32x16 z;
#pragma unroll
      for (int r = 0; r < 16; ++r) z[r] = 0.f;
      __builtin_amdgcn_s_setprio(1);
#pragma unroll
      for (int ka = 0; ka < 4; ++ka) {
        bf16x8 kf = *(const bf16x8*)&kbase[((2 * ka + hi) ^ (row & 7)) * 8];
        z = MFMA32(kf, qf[ka], z);
      }
      __builtin_amdgcn_s_setprio(0);
      st[tt] = z;
    }

    // ---- fixed-base softmax: p = exp2(s) raw (scale cancels in o = sum(p*v)/sum(p)) ----
    const u32 wt0 = (u32)(w >> (4 * hi));
    const u32 wt1 = (u32)(w >> (32 + 4 * hi));
#pragma unroll
    for (int tt = 0; tt < 2; ++tt) {
      const u32 wt = tt ? wt1 : wt0;
#pragma unroll
      for (int r = 0; r < 16; ++r) {
        const int bit = (r & 3) + 8 * (r >> 2);
        const float p = __builtin_amdgcn_exp2f((float)st[tt][r]);
        st[tt][r] = ((wt >> bit) & 1u) ? p : 0.f;
      }
    }

    // ---- pb = straight pack of st under the shared k-map ----
    u32x4 pb[4];
#pragma unroll
    for (int ks = 0; ks < 4; ++ks) {
      const int tt = ks >> 1, e = ks & 1;
#pragma unroll
      for (int w2 = 0; w2 < 4; ++w2)
        pb[ks][w2] = pk2((float)st[tt][8 * e + 2 * w2], (float)st[tt][8 * e + 2 * w2 + 1]);
    }

    // ---- l += colsum via ones-MFMA; PV with single-b128 V-frags ----
    __builtin_amdgcn_s_setprio(1);
#pragma unroll
    for (int ks = 0; ks < 4; ++ks)
      lacc = MFMA32(ones8, __builtin_bit_cast(bf16x8, pb[ks]), lacc);
#pragma unroll
    for (int dt = 0; dt < 2; ++dt) {
      const int row = 32 * dt + ql;
      const bf16* vbase = &Vs[buf][row * 64];
#pragma unroll
      for (int ks = 0; ks < 4; ++ks) {
        bf16x8 vf = *(const bf16x8*)&vbase[((2 * ks + hi) ^ (row & 7)) * 8];
        oacc[dt] = MFMA32(vf, __builtin_bit_cast(bf16x8, pb[ks]), oacc[dt]);
      }
    }
    __builtin_amdgcn_s_setprio(0);

    // stage + mask ops were issued a full compute ago -> retire instantly
    asm volatile("s_waitcnt vmcnt(0)" ::: "memory");
    __builtin_amdgcn_s_barrier();
    __builtin_amdgcn_sched_barrier(0);
    w = wn;
  }

  const float lsum = lacc[0];  // every reg row holds the same column-sum
  if constexpr (SPLITS > 1) {
    bf16* opr = opart + ((size_t)(half * 32 + bh) * Sc + qrow) * 64;
#pragma unroll
    for (int dt = 0; dt < 2; ++dt)
#pragma unroll
      for (int i = 0; i < 4; ++i) {
        bf16x4 o4;
#pragma unroll
        for (int rr = 0; rr < 4; ++rr) o4[rr] = (bf16)oacc[dt][4 * i + rr];
        *(bf16x4*)&opr[32 * dt + 8 * i + 4 * hi] = o4;
      }
    if (hi == 0) lsums[(size_t)(half * 32 + bh) * Sc + qrow] = lsum;
  } else {
    const float rinv = 1.f / fmaxf(lsum, 1e-35f);
    bf16* cp = ctx + (size_t)(b * Sc + qrow) * Dc + h * DKc;
#pragma unroll
    for (int dt = 0; dt < 2; ++dt)
#pragma unroll
      for (int i = 0; i < 4; ++i) {
        bf16x4 o4;
#pragma unroll
        for (int rr = 0; rr < 4; ++rr) o4[rr] = (bf16)(oacc[dt][4 * i + rr] * rinv);
        *(bf16x4*)&cp[32 * dt + 8 * i + 4 * hi] = o4;
      }
  }
}

// ---------------- combine NS fixed-base splits (bf16 partials, f32 l-sums) ----------------
template <int NS>
__global__ __launch_bounds__(256) void combine_kernel(const bf16* __restrict__ op,
                                                      const float* __restrict__ ls,
                                                      bf16* __restrict__ ctx) {
  const int wv = threadIdx.x >> 6, lane = threadIdx.x & 63;
  const size_t row = (size_t)blockIdx.x * 4 + wv;      // bh*2048 + q, 0..65535
  const int bh = (int)(row >> 11), q = (int)(row & 2047);
  const int b = bh >> 4, h = bh & 15;
  float o = 0.f, l = 0.f;
#pragma unroll
  for (int s = 0; s < NS; ++s) {
    o += (float)op[(size_t)s * 65536 * 64 + row * 64 + lane];
    l += ls[(size_t)s * 65536 + row];
  }
  ctx[((size_t)(b * Sc + q)) * Dc + h * DKc + lane] = (bf16)(o / fmaxf(l, 1e-35f));
}

extern "C" void kernel_launch(void* const* d_in, const int* in_sizes, int n_in,
                              void* d_out, int out_size, void* d_ws, size_t ws_size,
                              hipStream_t stream) {
  (void)in_sizes; (void)n_in; (void)out_size;
  const float* q  = (const float*)d_in[0];
  const float* k  = (const float*)d_in[1];
  const float* v  = (const float*)d_in[2];
  const float* Wq = (const float*)d_in[3];
  const float* bq = (const float*)d_in[4];
  const float* Wk = (const float*)d_in[5];
  const float* bk = (const float*)d_in[6];
  const float* Wv = (const float*)d_in[7];
  const float* bv = (const float*)d_in[8];
  const float* Wo = (const float*)d_in[9];
  const float* bo = (const float*)d_in[10];
  const int* mask = (const int*)d_in[11];

  char* ws = (char*)d_ws;
  size_t off = 0;
  auto take = [&](size_t bytes) -> void* {
    void* p = ws + off;
    off += (bytes + 255) & ~(size_t)255;
    return p;
  };
  bf16* qh  = (bf16*)take((size_t)Mc * Dc * 2);
  bf16* kh  = (bf16*)take((size_t)Mc * Dc * 2);
  bf16* vt  = (bf16*)take((size_t)Mc * Dc * 2);
  bf16* ctx = (bf16*)take((size_t)Mc * Dc * 2);
  u64* mbits = (u64*)take((size_t)Bc * Sc * MW * 8);   // transposed: [b][kw][q]
  bf16* wqb = (bf16*)take((size_t)Dc * Dc * 2);
  bf16* wkb = (bf16*)take((size_t)Dc * Dc * 2);
  bf16* wvb = (bf16*)take((size_t)Dc * Dc * 2);
  bf16* wob = (bf16*)take((size_t)Dc * Dc * 2);

  // split-KV partials (splits=2): bf16 [half*32+bh][q][64] + f32 l [half*32+bh][q]
  const size_t opart_sz = (size_t)32 * Sc * 64 * 2;    // per split (bf16)
  const size_t ls_sz    = (size_t)32 * Sc * 4;         // per split (f32)
  int splits = 1;
  bf16* opart = nullptr; float* lsums = nullptr;
  if (off + (opart_sz + ls_sz) * 2 <= ws_size) {
    splits = 2;
    opart = (bf16*)(ws + off);
    lsums = (float*)(ws + off + opart_sz * 2);
  }

  prep_kernel<<<dim3(2048, 5), 256, 0, stream>>>(Wq, Wk, Wv, Wo, mask,
                                                 wqb, wkb, wvb, wob, mbits);
  gemm_qkv_kernel<<<768, 256, 0, stream>>>(q, k, v, wqb, wkb, wvb, bq, bk, bv, qh, kh, vt);
  if (splits == 2) {
    attn_kernel<2><<<512, 512, 0, stream>>>(qh, kh, vt, mbits, ctx, opart, lsums);
    combine_kernel<2><<<16384, 256, 0, stream>>>(opart, lsums, ctx);
  } else {
    attn_kernel<1><<<256, 512, 0, stream>>>(qh, kh, vt, mbits, ctx, opart, lsums);
  }
  gemm_o_kernel<<<1024, 256, 0, stream>>>(ctx, wob, bo, (float*)d_out);
}